// Round 13
// baseline (309.711 us; speedup 1.0000x reference)
//
#include <hip/hip_runtime.h>

#define NODES 50000
#define CH 128
#define ELLW 64

using frag_ab = __attribute__((ext_vector_type(8))) short;   // 8 bf16
using frag_cd = __attribute__((ext_vector_type(4))) float;   // 4 fp32

__device__ __forceinline__ float bf2f(ushort u) {
    union { unsigned u; float f; } v; v.u = ((unsigned)u) << 16; return v.f;
}
__device__ __forceinline__ ushort f2bf(float f) {
    union { float f; unsigned u; } v; v.f = f;
    unsigned r = v.u + 0x7fff + ((v.u >> 16) & 1);   // RNE
    return (ushort)(r >> 16);
}

// ---------------- prep: 5 weight transposes + deg zeroing, ONE dispatch ----------------
__global__ void prep_weights(const float* __restrict__ Wlin,
                             const float* __restrict__ W1l, const float* __restrict__ W1r,
                             const float* __restrict__ W2l, const float* __restrict__ W2r,
                             ushort* __restrict__ o0, ushort* __restrict__ o1,
                             ushort* __restrict__ o2, ushort* __restrict__ o3,
                             ushort* __restrict__ o4, int* __restrict__ deg) {
    int b = blockIdx.x;
    if (b >= 448) {
        int i = (b - 448) * 256 + threadIdx.y * 128 + threadIdx.x;
        if (i < NODES) deg[i] = 0;
        return;
    }
    const float* W; ushort* O; int K; int kb;
    if (b < 192) { W = Wlin; O = o0; K = 384; kb = b; }
    else {
        int j = (b - 192) >> 6; kb = (b - 192) & 63; K = 128;
        W = (j == 0) ? W1l : (j == 1) ? W1r : (j == 2) ? W2l : W2r;
        O = (j == 0) ? o1  : (j == 1) ? o2  : (j == 2) ? o3  : o4;
    }
    int k = kb * 2 + threadIdx.y;
    int n = threadIdx.x;
    if (k < K) O[(size_t)n * K + k] = f2bf(W[(size_t)k * 128 + n]);
}

// ---------------- merged: gemm_lin 64-row tiles (blocks < GB) + fill_ell x2 ----------------
// 64x128 tile, 2x2 waves each 32x64 (2x4 MFMA frags). LDS 12 KB.
__global__ __launch_bounds__(256) void lin_and_ell(
    const float* __restrict__ A, const ushort* __restrict__ Wt,
    const float* __restrict__ bias, ushort* __restrict__ out, int N, int GB,
    const int* __restrict__ ei, int E, int* __restrict__ deg, int* __restrict__ ell)
{
    __shared__ ushort As[64 * 32];
    __shared__ ushort Bs[128 * 32];
    if (blockIdx.x >= GB) {
        int e0 = ((blockIdx.x - GB) * 256 + threadIdx.x) * 2;
#pragma unroll
        for (int j = 0; j < 2; ++j) {
            int e = e0 + j;
            if (e < E) {
                int d = ei[E + e];
                int pos = atomicAdd(&deg[d], 1);
                if (pos < ELLW) ell[(size_t)d * ELLW + pos] = ei[e];
            }
        }
        return;
    }
    const int tid = threadIdx.x;
    const int lane = tid & 63;
    const int wave = tid >> 6;
    const int wr = wave >> 1, wc = wave & 1;
    const int row0 = blockIdx.x * 64;
    const int l15 = lane & 15, quad = lane >> 4;

    frag_cd acc[2][4];
#pragma unroll
    for (int i = 0; i < 2; ++i)
#pragma unroll
        for (int j = 0; j < 4; ++j) acc[i][j] = (frag_cd){0.f, 0.f, 0.f, 0.f};

#pragma unroll 1
    for (int k0 = 0; k0 < 384; k0 += 32) {
        __syncthreads();
        // A tile: 64 rows x 32 k fp32 -> bf16; 512 float4, 2/thread
#pragma unroll
        for (int i = 0; i < 2; ++i) {
            int e = i * 256 + tid;
            int r = e >> 3, q = e & 7;
            int gr = row0 + r; if (gr > N - 1) gr = N - 1;
            float4 v = *(const float4*)(A + (size_t)gr * 384 + k0 + q * 4);
            ushort4 o; o.x = f2bf(v.x); o.y = f2bf(v.y); o.z = f2bf(v.z); o.w = f2bf(v.w);
            *(ushort4*)(As + r * 32 + q * 4) = o;
        }
        // B tile: 128 n x 32 k; 512 uint4, 2/thread
#pragma unroll
        for (int i = 0; i < 2; ++i) {
            int e = i * 256 + tid;
            uint4 v = *(const uint4*)(Wt + (size_t)(e >> 2) * 384 + k0 + (e & 3) * 8);
            *(uint4*)(Bs + e * 8) = v;
        }
        __syncthreads();

        frag_ab a[2], b[4];
#pragma unroll
        for (int i = 0; i < 2; ++i)
            a[i] = *(const frag_ab*)(As + (wr * 32 + i * 16 + l15) * 32 + quad * 8);
#pragma unroll
        for (int j = 0; j < 4; ++j)
            b[j] = *(const frag_ab*)(Bs + (wc * 64 + j * 16 + l15) * 32 + quad * 8);
#pragma unroll
        for (int i = 0; i < 2; ++i)
#pragma unroll
            for (int j = 0; j < 4; ++j)
                acc[i][j] = __builtin_amdgcn_mfma_f32_16x16x32_bf16(a[i], b[j], acc[i][j], 0, 0, 0);
    }

#pragma unroll
    for (int i = 0; i < 2; ++i)
#pragma unroll
        for (int r = 0; r < 4; ++r) {
            int row = row0 + wr * 32 + i * 16 + quad * 4 + r;
            if (row < N)
#pragma unroll
                for (int j = 0; j < 4; ++j) {
                    int col = wc * 64 + j * 16 + l15;
                    out[(size_t)row * 128 + col] = f2bf(acc[i][j][r] + bias[col]);
                }
        }
}

// ---------------- mean aggregation over ELL ----------------
__device__ __forceinline__ void acc8(float* acc, uint4 v) {
    acc[0] += bf2f((ushort)(v.x & 0xffff)); acc[1] += bf2f((ushort)(v.x >> 16));
    acc[2] += bf2f((ushort)(v.y & 0xffff)); acc[3] += bf2f((ushort)(v.y >> 16));
    acc[4] += bf2f((ushort)(v.z & 0xffff)); acc[5] += bf2f((ushort)(v.z >> 16));
    acc[6] += bf2f((ushort)(v.w & 0xffff)); acc[7] += bf2f((ushort)(v.w >> 16));
}

__global__ __launch_bounds__(256) void aggregate_ell(
    const ushort* __restrict__ h, const int* __restrict__ ell,
    const int* __restrict__ deg, ushort* __restrict__ mean, int N) {
    int node = blockIdx.x * 4 + (threadIdx.x >> 6);
    if (node >= N) return;
    int lane = threadIdx.x & 63;
    int g = lane >> 4;
    int q = lane & 15;
    const int* row = ell + (size_t)node * ELLW;
    int d = deg[node];
    int dc = d < ELLW ? d : ELLW;

    float acc[8];
#pragma unroll
    for (int k = 0; k < 8; ++k) acc[k] = 0.f;

    int n = 0;
    for (; n + 16 <= dc; n += 16) {
        int i0 = row[n + g];
        int i1 = row[n + 4 + g];
        int i2 = row[n + 8 + g];
        int i3 = row[n + 12 + g];
        uint4 v0 = *(const uint4*)(h + (size_t)i0 * CH + q * 8);
        uint4 v1 = *(const uint4*)(h + (size_t)i1 * CH + q * 8);
        uint4 v2 = *(const uint4*)(h + (size_t)i2 * CH + q * 8);
        uint4 v3 = *(const uint4*)(h + (size_t)i3 * CH + q * 8);
        acc8(acc, v0); acc8(acc, v1); acc8(acc, v2); acc8(acc, v3);
    }
    for (; n + 8 <= dc; n += 8) {
        int i0 = row[n + g];
        int i1 = row[n + 4 + g];
        uint4 v0 = *(const uint4*)(h + (size_t)i0 * CH + q * 8);
        uint4 v1 = *(const uint4*)(h + (size_t)i1 * CH + q * 8);
        acc8(acc, v0); acc8(acc, v1);
    }
    for (; n < dc; n += 4) {
        int j = n + g;
        if (j < dc) {
            int i0 = row[j];
            uint4 v0 = *(const uint4*)(h + (size_t)i0 * CH + q * 8);
            acc8(acc, v0);
        }
    }
#pragma unroll
    for (int k = 0; k < 8; ++k) {
        acc[k] += __shfl_xor(acc[k], 16, 64);
        acc[k] += __shfl_xor(acc[k], 32, 64);
    }
    if (g == 0) {
        float inv = 1.f / fmaxf((float)d, 1.f);
        uint4 o;
        o.x = ((uint)f2bf(acc[1] * inv) << 16) | (uint)f2bf(acc[0] * inv);
        o.y = ((uint)f2bf(acc[3] * inv) << 16) | (uint)f2bf(acc[2] * inv);
        o.z = ((uint)f2bf(acc[5] * inv) << 16) | (uint)f2bf(acc[4] * inv);
        o.w = ((uint)f2bf(acc[7] * inv) << 16) | (uint)f2bf(acc[6] * inv);
        *(uint4*)(mean + (size_t)node * CH + q * 8) = o;
    }
}

// ---------------- dual-input MFMA GEMM, 64-row tiles: out = A1@Wt1^T + A2@Wt2^T + bias ----
template <bool RELU>
__global__ __launch_bounds__(256) void mfma_gemm(
    const ushort* __restrict__ A1, const ushort* __restrict__ Wt1,
    const ushort* __restrict__ A2, const ushort* __restrict__ Wt2,
    const float* __restrict__ bias, ushort* __restrict__ out, int N)
{
    __shared__ ushort As[64 * 32];
    __shared__ ushort Bs[128 * 32];
    const int tid = threadIdx.x;
    const int lane = tid & 63;
    const int wave = tid >> 6;
    const int wr = wave >> 1, wc = wave & 1;
    const int row0 = blockIdx.x * 64;
    const int l15 = lane & 15, quad = lane >> 4;

    frag_cd acc[2][4];
#pragma unroll
    for (int i = 0; i < 2; ++i)
#pragma unroll
        for (int j = 0; j < 4; ++j) acc[i][j] = (frag_cd){0.f, 0.f, 0.f, 0.f};

#pragma unroll 1
    for (int part = 0; part < 2; ++part) {
        const ushort* A  = part ? A2 : A1;
        const ushort* Wt = part ? Wt2 : Wt1;

#pragma unroll 1
        for (int k0 = 0; k0 < 128; k0 += 32) {
            __syncthreads();
            // A tile: 64 rows x 32 k; 256 uint4, 1/thread
            {
                int r = tid >> 2, kq = tid & 3;
                int gr = row0 + r; if (gr > N - 1) gr = N - 1;
                uint4 v = *(const uint4*)(A + (size_t)gr * 128 + k0 + kq * 8);
                *(uint4*)(As + tid * 8) = v;
            }
            // B tile: 128 n x 32 k; 512 uint4, 2/thread
#pragma unroll
            for (int i = 0; i < 2; ++i) {
                int e = i * 256 + tid;
                uint4 v = *(const uint4*)(Wt + (size_t)(e >> 2) * 128 + k0 + (e & 3) * 8);
                *(uint4*)(Bs + e * 8) = v;
            }
            __syncthreads();

            frag_ab a[2], b[4];
#pragma unroll
            for (int i = 0; i < 2; ++i)
                a[i] = *(const frag_ab*)(As + (wr * 32 + i * 16 + l15) * 32 + quad * 8);
#pragma unroll
            for (int j = 0; j < 4; ++j)
                b[j] = *(const frag_ab*)(Bs + (wc * 64 + j * 16 + l15) * 32 + quad * 8);
#pragma unroll
            for (int i = 0; i < 2; ++i)
#pragma unroll
                for (int j = 0; j < 4; ++j)
                    acc[i][j] = __builtin_amdgcn_mfma_f32_16x16x32_bf16(a[i], b[j], acc[i][j], 0, 0, 0);
        }
    }

#pragma unroll
    for (int i = 0; i < 2; ++i)
#pragma unroll
        for (int r = 0; r < 4; ++r) {
            int row = row0 + wr * 32 + i * 16 + quad * 4 + r;
            if (row < N)
#pragma unroll
                for (int j = 0; j < 4; ++j) {
                    int col = wc * 64 + j * 16 + l15;
                    float v = acc[i][j][r] + bias[col];
                    if (RELU) v = fmaxf(v, 0.f);
                    out[(size_t)row * 128 + col] = f2bf(v);
                }
        }
}

// ---------------- classifier: 8 edges / 16-lane group ----------------
__device__ __forceinline__ float dot8(uint4 va, uint4 vb) {
    float p = 0.f;
    p += bf2f((ushort)(va.x & 0xffff)) * bf2f((ushort)(vb.x & 0xffff));
    p += bf2f((ushort)(va.x >> 16))    * bf2f((ushort)(vb.x >> 16));
    p += bf2f((ushort)(va.y & 0xffff)) * bf2f((ushort)(vb.y & 0xffff));
    p += bf2f((ushort)(va.y >> 16))    * bf2f((ushort)(vb.y >> 16));
    p += bf2f((ushort)(va.z & 0xffff)) * bf2f((ushort)(vb.z & 0xffff));
    p += bf2f((ushort)(va.z >> 16))    * bf2f((ushort)(vb.z >> 16));
    p += bf2f((ushort)(va.w & 0xffff)) * bf2f((ushort)(vb.w & 0xffff));
    p += bf2f((ushort)(va.w >> 16))    * bf2f((ushort)(vb.w >> 16));
    return p;
}

__global__ __launch_bounds__(256) void classify_bf(
    const ushort* __restrict__ h2, const int* __restrict__ eli,
    int EL, float* __restrict__ out) {
    int gt = blockIdx.x * blockDim.x + threadIdx.x;
    int g0 = (gt >> 4) * 8;
    int lane = gt & 15;
    if (g0 >= EL) return;
    bool full = (g0 + 7 < EL);
    int ha[8], ta[8];
    if (full) {
        int4 h0 = *(const int4*)(eli + g0);
        int4 h1 = *(const int4*)(eli + g0 + 4);
        int4 t0 = *(const int4*)(eli + EL + g0);
        int4 t1 = *(const int4*)(eli + EL + g0 + 4);
        ha[0] = h0.x; ha[1] = h0.y; ha[2] = h0.z; ha[3] = h0.w;
        ha[4] = h1.x; ha[5] = h1.y; ha[6] = h1.z; ha[7] = h1.w;
        ta[0] = t0.x; ta[1] = t0.y; ta[2] = t0.z; ta[3] = t0.w;
        ta[4] = t1.x; ta[5] = t1.y; ta[6] = t1.z; ta[7] = t1.w;
    } else {
#pragma unroll
        for (int j = 0; j < 8; ++j) {
            int gj = (g0 + j < EL) ? g0 + j : EL - 1;
            ha[j] = eli[gj];
            ta[j] = eli[EL + gj];
        }
    }
    uint4 va[8], vb[8];
#pragma unroll
    for (int j = 0; j < 8; ++j) {
        va[j] = *((const uint4*)(h2 + (size_t)ha[j] * CH) + lane);
        vb[j] = *((const uint4*)(h2 + (size_t)ta[j] * CH) + lane);
    }
    float p[8];
#pragma unroll
    for (int j = 0; j < 8; ++j) p[j] = dot8(va[j], vb[j]);
#pragma unroll
    for (int s = 8; s >= 1; s >>= 1) {
#pragma unroll
        for (int j = 0; j < 8; ++j) p[j] += __shfl_down(p[j], s, 16);
    }
    if (lane == 0) {
        if (full) {
            *(float4*)(out + g0)     = make_float4(p[0], p[1], p[2], p[3]);
            *(float4*)(out + g0 + 4) = make_float4(p[4], p[5], p[6], p[7]);
        } else {
#pragma unroll
            for (int j = 0; j < 8; ++j)
                if (g0 + j < EL) out[g0 + j] = p[j];
        }
    }
}

extern "C" void kernel_launch(void* const* d_in, const int* in_sizes, int n_in,
                              void* d_out, int out_size, void* d_ws, size_t ws_size,
                              hipStream_t stream) {
    const float* x     = (const float*)d_in[0];
    const int*   ei    = (const int*)d_in[1];
    const int*   eli   = (const int*)d_in[2];
    const float* W_lin = (const float*)d_in[3];
    const float* b_lin = (const float*)d_in[4];
    const float* W1l   = (const float*)d_in[5];
    const float* b1    = (const float*)d_in[6];
    const float* W1r   = (const float*)d_in[7];
    const float* W2l   = (const float*)d_in[8];
    const float* b2    = (const float*)d_in[9];
    const float* W2r   = (const float*)d_in[10];
    float* out = (float*)d_out;

    const int E  = in_sizes[1] / 2;
    const int EL = in_sizes[2] / 2;
    const int N  = NODES;

    char* ws = (char*)d_ws;
    size_t off = 0;
    auto alloc = [&](size_t bytes) -> void* {
        void* p = ws + off;
        off += (bytes + 255) & ~(size_t)255;
        return p;
    };
    ushort* n0    = (ushort*)alloc((size_t)N * CH * sizeof(ushort));  // h0, then h2
    ushort* n1    = (ushort*)alloc((size_t)N * CH * sizeof(ushort));  // mean1 / mean2
    ushort* n2    = (ushort*)alloc((size_t)N * CH * sizeof(ushort));  // h1
    ushort* WtLin = (ushort*)alloc((size_t)CH * 384 * sizeof(ushort));
    ushort* Wt1l  = (ushort*)alloc((size_t)CH * CH * sizeof(ushort));
    ushort* Wt1r  = (ushort*)alloc((size_t)CH * CH * sizeof(ushort));
    ushort* Wt2l  = (ushort*)alloc((size_t)CH * CH * sizeof(ushort));
    ushort* Wt2r  = (ushort*)alloc((size_t)CH * CH * sizeof(ushort));
    int* deg = (int*)alloc((size_t)N * sizeof(int));
    int* ell = (int*)alloc((size_t)N * ELLW * sizeof(int));
    (void)ws_size; (void)n_in; (void)out_size;

    const int GB  = (N + 63) / 64;              // 782 gemm tiles (64 rows each)
    const int EB2 = (E + 511) / 512;            // 1563 fill blocks (2 edges/thread)
    const int AB  = (N + 3) / 4;                // 12500 agg groups

    // 1) weight transposes + deg zeroing (one dispatch)
    prep_weights<<<dim3(644), dim3(128, 2), 0, stream>>>(
        W_lin, W1l, W1r, W2l, W2r, WtLin, Wt1l, Wt1r, Wt2l, Wt2r, deg);

    // 2) h0 = bf16(x)@W_lin + b_lin  OVERLAPPED WITH  ELL build
    lin_and_ell<<<dim3(GB + EB2), dim3(256), 0, stream>>>(
        x, WtLin, b_lin, n0, N, GB, ei, E, deg, ell);

    // 3) layer 1: mean1 -> n1; h1 = relu(mean1@W1l + h0@W1r + b1) -> n2
    aggregate_ell<<<dim3(AB), dim3(256), 0, stream>>>(n0, ell, deg, n1, N);
    mfma_gemm<true><<<dim3(GB), dim3(256), 0, stream>>>(
        n1, Wt1l, n0, Wt1r, b1, n2, N);

    // 4) layer 2: mean2 -> n1; h2 = mean2@W2l + h1@W2r + b2 -> n0
    aggregate_ell<<<dim3(AB), dim3(256), 0, stream>>>(n2, ell, deg, n1, N);
    mfma_gemm<false><<<dim3(GB), dim3(256), 0, stream>>>(
        n1, Wt2l, n2, Wt2r, b2, n0, N);

    // 5) classifier on h2 = n0
    long long groups = ((long long)EL + 7) / 8;
    long long cls_threads = groups * 16;
    classify_bf<<<dim3((int)((cls_threads + 255) / 256)), dim3(256), 0, stream>>>(
        n0, eli, EL, out);
}

// Round 14
// 301.798 us; speedup vs baseline: 1.0262x; 1.0262x over previous
//
#include <hip/hip_runtime.h>

#define NODES 50000
#define CH 128
#define ELLW 64

using frag_ab = __attribute__((ext_vector_type(8))) short;   // 8 bf16
using frag_cd = __attribute__((ext_vector_type(4))) float;   // 4 fp32

__device__ __forceinline__ float bf2f(ushort u) {
    union { unsigned u; float f; } v; v.u = ((unsigned)u) << 16; return v.f;
}
__device__ __forceinline__ ushort f2bf(float f) {
    union { float f; unsigned u; } v; v.f = f;
    unsigned r = v.u + 0x7fff + ((v.u >> 16) & 1);   // RNE
    return (ushort)(r >> 16);
}

// ---------------- prep: 5 weight transposes + deg zeroing, ONE dispatch ----------------
__global__ void prep_weights(const float* __restrict__ Wlin,
                             const float* __restrict__ W1l, const float* __restrict__ W1r,
                             const float* __restrict__ W2l, const float* __restrict__ W2r,
                             ushort* __restrict__ o0, ushort* __restrict__ o1,
                             ushort* __restrict__ o2, ushort* __restrict__ o3,
                             ushort* __restrict__ o4, int* __restrict__ deg) {
    int b = blockIdx.x;
    if (b >= 448) {
        int i = (b - 448) * 256 + threadIdx.y * 128 + threadIdx.x;
        if (i < NODES) deg[i] = 0;
        return;
    }
    const float* W; ushort* O; int K; int kb;
    if (b < 192) { W = Wlin; O = o0; K = 384; kb = b; }
    else {
        int j = (b - 192) >> 6; kb = (b - 192) & 63; K = 128;
        W = (j == 0) ? W1l : (j == 1) ? W1r : (j == 2) ? W2l : W2r;
        O = (j == 0) ? o1  : (j == 1) ? o2  : (j == 2) ? o3  : o4;
    }
    int k = kb * 2 + threadIdx.y;
    int n = threadIdx.x;
    if (k < K) O[(size_t)n * K + k] = f2bf(W[(size_t)k * 128 + n]);
}

// ---------------- merged: gemm_lin 128-row tiles (blocks < GB) + fill_ell x2 ----------------
// 128x128 tile (16 KB LDS): big tile keeps gemm role hidden behind fill role's ceiling;
// round-13's 64-row tile regressed this kernel 56.7 -> 67 us.
__global__ __launch_bounds__(256) void lin_and_ell(
    const float* __restrict__ A, const ushort* __restrict__ Wt,
    const float* __restrict__ bias, ushort* __restrict__ out, int N, int GB,
    const int* __restrict__ ei, int E, int* __restrict__ deg, int* __restrict__ ell)
{
    __shared__ ushort As[128 * 32];
    __shared__ ushort Bs[128 * 32];
    if (blockIdx.x >= GB) {
        int e0 = ((blockIdx.x - GB) * 256 + threadIdx.x) * 2;
#pragma unroll
        for (int j = 0; j < 2; ++j) {
            int e = e0 + j;
            if (e < E) {
                int d = ei[E + e];
                int pos = atomicAdd(&deg[d], 1);
                if (pos < ELLW) ell[(size_t)d * ELLW + pos] = ei[e];
            }
        }
        return;
    }
    const int tid = threadIdx.x;
    const int lane = tid & 63;
    const int wave = tid >> 6;
    const int wr = wave >> 1, wc = wave & 1;
    const int row0 = blockIdx.x * 128;
    const int l15 = lane & 15, quad = lane >> 4;

    frag_cd acc[4][4];
#pragma unroll
    for (int i = 0; i < 4; ++i)
#pragma unroll
        for (int j = 0; j < 4; ++j) acc[i][j] = (frag_cd){0.f, 0.f, 0.f, 0.f};

#pragma unroll 1
    for (int k0 = 0; k0 < 384; k0 += 32) {
        __syncthreads();
#pragma unroll
        for (int i = 0; i < 4; ++i) {
            int e = i * 256 + tid;
            int r = e >> 3, q = e & 7;
            int gr = row0 + r; if (gr > N - 1) gr = N - 1;
            float4 v = *(const float4*)(A + (size_t)gr * 384 + k0 + q * 4);
            ushort4 o; o.x = f2bf(v.x); o.y = f2bf(v.y); o.z = f2bf(v.z); o.w = f2bf(v.w);
            *(ushort4*)(As + r * 32 + q * 4) = o;
        }
#pragma unroll
        for (int i = 0; i < 2; ++i) {
            int e = i * 256 + tid;
            uint4 v = *(const uint4*)(Wt + (size_t)(e >> 2) * 384 + k0 + (e & 3) * 8);
            *(uint4*)(Bs + e * 8) = v;
        }
        __syncthreads();

        frag_ab a[4], b[4];
#pragma unroll
        for (int i = 0; i < 4; ++i)
            a[i] = *(const frag_ab*)(As + (wr * 64 + i * 16 + l15) * 32 + quad * 8);
#pragma unroll
        for (int j = 0; j < 4; ++j)
            b[j] = *(const frag_ab*)(Bs + (wc * 64 + j * 16 + l15) * 32 + quad * 8);
#pragma unroll
        for (int i = 0; i < 4; ++i)
#pragma unroll
            for (int j = 0; j < 4; ++j)
                acc[i][j] = __builtin_amdgcn_mfma_f32_16x16x32_bf16(a[i], b[j], acc[i][j], 0, 0, 0);
    }

#pragma unroll
    for (int i = 0; i < 4; ++i)
#pragma unroll
        for (int r = 0; r < 4; ++r) {
            int row = row0 + wr * 64 + i * 16 + quad * 4 + r;
            if (row < N)
#pragma unroll
                for (int j = 0; j < 4; ++j) {
                    int col = wc * 64 + j * 16 + l15;
                    out[(size_t)row * 128 + col] = f2bf(acc[i][j][r] + bias[col]);
                }
        }
}

// ---------------- mean aggregation over ELL ----------------
__device__ __forceinline__ void acc8(float* acc, uint4 v) {
    acc[0] += bf2f((ushort)(v.x & 0xffff)); acc[1] += bf2f((ushort)(v.x >> 16));
    acc[2] += bf2f((ushort)(v.y & 0xffff)); acc[3] += bf2f((ushort)(v.y >> 16));
    acc[4] += bf2f((ushort)(v.z & 0xffff)); acc[5] += bf2f((ushort)(v.z >> 16));
    acc[6] += bf2f((ushort)(v.w & 0xffff)); acc[7] += bf2f((ushort)(v.w >> 16));
}

__global__ __launch_bounds__(256) void aggregate_ell(
    const ushort* __restrict__ h, const int* __restrict__ ell,
    const int* __restrict__ deg, ushort* __restrict__ mean, int N) {
    int node = blockIdx.x * 4 + (threadIdx.x >> 6);
    if (node >= N) return;
    int lane = threadIdx.x & 63;
    int g = lane >> 4;
    int q = lane & 15;
    const int* row = ell + (size_t)node * ELLW;
    int d = deg[node];
    int dc = d < ELLW ? d : ELLW;

    float acc[8];
#pragma unroll
    for (int k = 0; k < 8; ++k) acc[k] = 0.f;

    int n = 0;
    for (; n + 16 <= dc; n += 16) {
        int i0 = row[n + g];
        int i1 = row[n + 4 + g];
        int i2 = row[n + 8 + g];
        int i3 = row[n + 12 + g];
        uint4 v0 = *(const uint4*)(h + (size_t)i0 * CH + q * 8);
        uint4 v1 = *(const uint4*)(h + (size_t)i1 * CH + q * 8);
        uint4 v2 = *(const uint4*)(h + (size_t)i2 * CH + q * 8);
        uint4 v3 = *(const uint4*)(h + (size_t)i3 * CH + q * 8);
        acc8(acc, v0); acc8(acc, v1); acc8(acc, v2); acc8(acc, v3);
    }
    for (; n + 8 <= dc; n += 8) {
        int i0 = row[n + g];
        int i1 = row[n + 4 + g];
        uint4 v0 = *(const uint4*)(h + (size_t)i0 * CH + q * 8);
        uint4 v1 = *(const uint4*)(h + (size_t)i1 * CH + q * 8);
        acc8(acc, v0); acc8(acc, v1);
    }
    for (; n < dc; n += 4) {
        int j = n + g;
        if (j < dc) {
            int i0 = row[j];
            uint4 v0 = *(const uint4*)(h + (size_t)i0 * CH + q * 8);
            acc8(acc, v0);
        }
    }
#pragma unroll
    for (int k = 0; k < 8; ++k) {
        acc[k] += __shfl_xor(acc[k], 16, 64);
        acc[k] += __shfl_xor(acc[k], 32, 64);
    }
    if (g == 0) {
        float inv = 1.f / fmaxf((float)d, 1.f);
        uint4 o;
        o.x = ((uint)f2bf(acc[1] * inv) << 16) | (uint)f2bf(acc[0] * inv);
        o.y = ((uint)f2bf(acc[3] * inv) << 16) | (uint)f2bf(acc[2] * inv);
        o.z = ((uint)f2bf(acc[5] * inv) << 16) | (uint)f2bf(acc[4] * inv);
        o.w = ((uint)f2bf(acc[7] * inv) << 16) | (uint)f2bf(acc[6] * inv);
        *(uint4*)(mean + (size_t)node * CH + q * 8) = o;
    }
}

// ---------------- dual-input MFMA GEMM, 64-row tiles (standalone: 782 blocks ~3/CU) ----
template <bool RELU>
__global__ __launch_bounds__(256) void mfma_gemm(
    const ushort* __restrict__ A1, const ushort* __restrict__ Wt1,
    const ushort* __restrict__ A2, const ushort* __restrict__ Wt2,
    const float* __restrict__ bias, ushort* __restrict__ out, int N)
{
    __shared__ ushort As[64 * 32];
    __shared__ ushort Bs[128 * 32];
    const int tid = threadIdx.x;
    const int lane = tid & 63;
    const int wave = tid >> 6;
    const int wr = wave >> 1, wc = wave & 1;
    const int row0 = blockIdx.x * 64;
    const int l15 = lane & 15, quad = lane >> 4;

    frag_cd acc[2][4];
#pragma unroll
    for (int i = 0; i < 2; ++i)
#pragma unroll
        for (int j = 0; j < 4; ++j) acc[i][j] = (frag_cd){0.f, 0.f, 0.f, 0.f};

#pragma unroll 1
    for (int part = 0; part < 2; ++part) {
        const ushort* A  = part ? A2 : A1;
        const ushort* Wt = part ? Wt2 : Wt1;

#pragma unroll 1
        for (int k0 = 0; k0 < 128; k0 += 32) {
            __syncthreads();
            {
                int r = tid >> 2, kq = tid & 3;
                int gr = row0 + r; if (gr > N - 1) gr = N - 1;
                uint4 v = *(const uint4*)(A + (size_t)gr * 128 + k0 + kq * 8);
                *(uint4*)(As + tid * 8) = v;
            }
#pragma unroll
            for (int i = 0; i < 2; ++i) {
                int e = i * 256 + tid;
                uint4 v = *(const uint4*)(Wt + (size_t)(e >> 2) * 128 + k0 + (e & 3) * 8);
                *(uint4*)(Bs + e * 8) = v;
            }
            __syncthreads();

            frag_ab a[2], b[4];
#pragma unroll
            for (int i = 0; i < 2; ++i)
                a[i] = *(const frag_ab*)(As + (wr * 32 + i * 16 + l15) * 32 + quad * 8);
#pragma unroll
            for (int j = 0; j < 4; ++j)
                b[j] = *(const frag_ab*)(Bs + (wc * 64 + j * 16 + l15) * 32 + quad * 8);
#pragma unroll
            for (int i = 0; i < 2; ++i)
#pragma unroll
                for (int j = 0; j < 4; ++j)
                    acc[i][j] = __builtin_amdgcn_mfma_f32_16x16x32_bf16(a[i], b[j], acc[i][j], 0, 0, 0);
        }
    }

#pragma unroll
    for (int i = 0; i < 2; ++i)
#pragma unroll
        for (int r = 0; r < 4; ++r) {
            int row = row0 + wr * 32 + i * 16 + quad * 4 + r;
            if (row < N)
#pragma unroll
                for (int j = 0; j < 4; ++j) {
                    int col = wc * 64 + j * 16 + l15;
                    float v = acc[i][j][r] + bias[col];
                    if (RELU) v = fmaxf(v, 0.f);
                    out[(size_t)row * 128 + col] = f2bf(v);
                }
        }
}

// ---------------- classifier: 8 edges / 16-lane group ----------------
__device__ __forceinline__ float dot8(uint4 va, uint4 vb) {
    float p = 0.f;
    p += bf2f((ushort)(va.x & 0xffff)) * bf2f((ushort)(vb.x & 0xffff));
    p += bf2f((ushort)(va.x >> 16))    * bf2f((ushort)(vb.x >> 16));
    p += bf2f((ushort)(va.y & 0xffff)) * bf2f((ushort)(vb.y & 0xffff));
    p += bf2f((ushort)(va.y >> 16))    * bf2f((ushort)(vb.y >> 16));
    p += bf2f((ushort)(va.z & 0xffff)) * bf2f((ushort)(vb.z & 0xffff));
    p += bf2f((ushort)(va.z >> 16))    * bf2f((ushort)(vb.z >> 16));
    p += bf2f((ushort)(va.w & 0xffff)) * bf2f((ushort)(vb.w & 0xffff));
    p += bf2f((ushort)(va.w >> 16))    * bf2f((ushort)(vb.w >> 16));
    return p;
}

__global__ __launch_bounds__(256) void classify_bf(
    const ushort* __restrict__ h2, const int* __restrict__ eli,
    int EL, float* __restrict__ out) {
    int gt = blockIdx.x * blockDim.x + threadIdx.x;
    int g0 = (gt >> 4) * 8;
    int lane = gt & 15;
    if (g0 >= EL) return;
    bool full = (g0 + 7 < EL);
    int ha[8], ta[8];
    if (full) {
        int4 h0 = *(const int4*)(eli + g0);
        int4 h1 = *(const int4*)(eli + g0 + 4);
        int4 t0 = *(const int4*)(eli + EL + g0);
        int4 t1 = *(const int4*)(eli + EL + g0 + 4);
        ha[0] = h0.x; ha[1] = h0.y; ha[2] = h0.z; ha[3] = h0.w;
        ha[4] = h1.x; ha[5] = h1.y; ha[6] = h1.z; ha[7] = h1.w;
        ta[0] = t0.x; ta[1] = t0.y; ta[2] = t0.z; ta[3] = t0.w;
        ta[4] = t1.x; ta[5] = t1.y; ta[6] = t1.z; ta[7] = t1.w;
    } else {
#pragma unroll
        for (int j = 0; j < 8; ++j) {
            int gj = (g0 + j < EL) ? g0 + j : EL - 1;
            ha[j] = eli[gj];
            ta[j] = eli[EL + gj];
        }
    }
    uint4 va[8], vb[8];
#pragma unroll
    for (int j = 0; j < 8; ++j) {
        va[j] = *((const uint4*)(h2 + (size_t)ha[j] * CH) + lane);
        vb[j] = *((const uint4*)(h2 + (size_t)ta[j] * CH) + lane);
    }
    float p[8];
#pragma unroll
    for (int j = 0; j < 8; ++j) p[j] = dot8(va[j], vb[j]);
#pragma unroll
    for (int s = 8; s >= 1; s >>= 1) {
#pragma unroll
        for (int j = 0; j < 8; ++j) p[j] += __shfl_down(p[j], s, 16);
    }
    if (lane == 0) {
        if (full) {
            *(float4*)(out + g0)     = make_float4(p[0], p[1], p[2], p[3]);
            *(float4*)(out + g0 + 4) = make_float4(p[4], p[5], p[6], p[7]);
        } else {
#pragma unroll
            for (int j = 0; j < 8; ++j)
                if (g0 + j < EL) out[g0 + j] = p[j];
        }
    }
}

extern "C" void kernel_launch(void* const* d_in, const int* in_sizes, int n_in,
                              void* d_out, int out_size, void* d_ws, size_t ws_size,
                              hipStream_t stream) {
    const float* x     = (const float*)d_in[0];
    const int*   ei    = (const int*)d_in[1];
    const int*   eli   = (const int*)d_in[2];
    const float* W_lin = (const float*)d_in[3];
    const float* b_lin = (const float*)d_in[4];
    const float* W1l   = (const float*)d_in[5];
    const float* b1    = (const float*)d_in[6];
    const float* W1r   = (const float*)d_in[7];
    const float* W2l   = (const float*)d_in[8];
    const float* b2    = (const float*)d_in[9];
    const float* W2r   = (const float*)d_in[10];
    float* out = (float*)d_out;

    const int E  = in_sizes[1] / 2;
    const int EL = in_sizes[2] / 2;
    const int N  = NODES;

    char* ws = (char*)d_ws;
    size_t off = 0;
    auto alloc = [&](size_t bytes) -> void* {
        void* p = ws + off;
        off += (bytes + 255) & ~(size_t)255;
        return p;
    };
    ushort* n0    = (ushort*)alloc((size_t)N * CH * sizeof(ushort));  // h0, then h2
    ushort* n1    = (ushort*)alloc((size_t)N * CH * sizeof(ushort));  // mean1 / mean2
    ushort* n2    = (ushort*)alloc((size_t)N * CH * sizeof(ushort));  // h1
    ushort* WtLin = (ushort*)alloc((size_t)CH * 384 * sizeof(ushort));
    ushort* Wt1l  = (ushort*)alloc((size_t)CH * CH * sizeof(ushort));
    ushort* Wt1r  = (ushort*)alloc((size_t)CH * CH * sizeof(ushort));
    ushort* Wt2l  = (ushort*)alloc((size_t)CH * CH * sizeof(ushort));
    ushort* Wt2r  = (ushort*)alloc((size_t)CH * CH * sizeof(ushort));
    int* deg = (int*)alloc((size_t)N * sizeof(int));
    int* ell = (int*)alloc((size_t)N * ELLW * sizeof(int));
    (void)ws_size; (void)n_in; (void)out_size;

    const int GB128 = (N + 127) / 128;          // 391 tiles for lin_and_ell gemm role
    const int GB64  = (N + 63) / 64;            // 782 tiles for standalone gemms
    const int EB2   = (E + 511) / 512;          // 1563 fill blocks (2 edges/thread)
    const int AB    = (N + 3) / 4;              // 12500 agg groups

    // 1) weight transposes + deg zeroing (one dispatch)
    prep_weights<<<dim3(644), dim3(128, 2), 0, stream>>>(
        W_lin, W1l, W1r, W2l, W2r, WtLin, Wt1l, Wt1r, Wt2l, Wt2r, deg);

    // 2) h0 = bf16(x)@W_lin + b_lin  OVERLAPPED WITH  ELL build
    lin_and_ell<<<dim3(GB128 + EB2), dim3(256), 0, stream>>>(
        x, WtLin, b_lin, n0, N, GB128, ei, E, deg, ell);

    // 3) layer 1: mean1 -> n1; h1 = relu(mean1@W1l + h0@W1r + b1) -> n2
    aggregate_ell<<<dim3(AB), dim3(256), 0, stream>>>(n0, ell, deg, n1, N);
    mfma_gemm<true><<<dim3(GB64), dim3(256), 0, stream>>>(
        n1, Wt1l, n0, Wt1r, b1, n2, N);

    // 4) layer 2: mean2 -> n1; h2 = mean2@W2l + h1@W2r + b2 -> n0
    aggregate_ell<<<dim3(AB), dim3(256), 0, stream>>>(n2, ell, deg, n1, N);
    mfma_gemm<false><<<dim3(GB64), dim3(256), 0, stream>>>(
        n1, Wt2l, n2, Wt2r, b2, n0, N);

    // 5) classifier on h2 = n0
    long long groups = ((long long)EL + 7) / 8;
    long long cls_threads = groups * 16;
    classify_bf<<<dim3((int)((cls_threads + 255) / 256)), dim3(256), 0, stream>>>(
        n0, eli, EL, out);
}